// Round 15
// baseline (889.902 us; speedup 1.0000x reference)
//
#include <hip/hip_runtime.h>
#include <stdint.h>

#define N_ACTIVE 200000
#define N_IN 64
#define N_OUT 64
#define K_FILT 27
#define R_PAIRS 100000
#define TOTP (K_FILT * R_PAIRS)          // 2,700,000
#define NSLOT (N_ACTIVE * K_FILT)        // 5,400,000 slots (row, kf)

#define CF_BLOCKS (N_ACTIVE * N_IN / 8 / 256)    // 6250
#define CW_BLOCKS K_FILT                          // 27
#define CL_BLOCKS ((TOTP + 255) / 256)            // 10547

typedef __bf16 bf16x8 __attribute__((ext_vector_type(8)));
typedef float f32x4 __attribute__((ext_vector_type(4)));

// ---------------------------------------------------------------------------
// fused prep: convert_feat | convert_wt | claim into PACKED int2 slot table
// slotP[slot] = { in1 | (cnt<<18), in2 }; 3rd+ duplicate -> overflow list
// ---------------------------------------------------------------------------
__global__ __launch_bounds__(256) void prep_fused(
    const float* __restrict__ feat, __bf16* __restrict__ featb,
    const float* __restrict__ wsrc, __bf16* __restrict__ wt,
    const int* __restrict__ in_idx, const int* __restrict__ out_idx,
    int* __restrict__ slotW,            // int view of slotP (x at 2*slot)
    int2* __restrict__ ovf, int* __restrict__ ovfCur)
{
    int bb = blockIdx.x, t = threadIdx.x;
    if (bb < CF_BLOCKS) {
        int i = bb * 256 + t;
        const f32x4* src = reinterpret_cast<const f32x4*>(feat) + 2 * (size_t)i;
        f32x4 v0 = __builtin_nontemporal_load(src);
        f32x4 v1 = __builtin_nontemporal_load(src + 1);
        bf16x8 o;
        o[0] = (__bf16)v0[0]; o[1] = (__bf16)v0[1]; o[2] = (__bf16)v0[2]; o[3] = (__bf16)v0[3];
        o[4] = (__bf16)v1[0]; o[5] = (__bf16)v1[1]; o[6] = (__bf16)v1[2]; o[7] = (__bf16)v1[3];
        reinterpret_cast<bf16x8*>(featb)[i] = o;
    } else if (bb < CF_BLOCKS + CW_BLOCKS) {
        int kf = bb - CF_BLOCKS;
        const float* wk = wsrc + kf * 4096;
        __bf16* wo = wt + kf * 4096;
        int o = t >> 2, i0 = (t & 3) * 16;
        bf16x8 a, b;
        #pragma unroll
        for (int j = 0; j < 8; ++j) a[j] = (__bf16)wk[(i0 + j) * 64 + o];
        #pragma unroll
        for (int j = 0; j < 8; ++j) b[j] = (__bf16)wk[(i0 + 8 + j) * 64 + o];
        *reinterpret_cast<bf16x8*>(wo + o * 64 + i0) = a;
        *reinterpret_cast<bf16x8*>(wo + o * 64 + i0 + 8) = b;
    } else {
        int p = (bb - CF_BLOCKS - CW_BLOCKS) * 256 + t;
        if (p < TOTP) {
            unsigned k = (unsigned)p / (unsigned)R_PAIRS;
            int row = out_idx[p];
            int iv  = in_idx[p];
            int slot = row * K_FILT + (int)k;
            int old = atomicAdd(&slotW[slot * 2], 1 << 18);
            int c = old >> 18;
            if (c == 0)      atomicOr(&slotW[slot * 2], iv);    // in1 bits
            else if (c == 1) slotW[slot * 2 + 1] = iv;          // sole writer
            else {
                int q = atomicAdd(ovfCur, 1);
                ovf[q] = make_int2(slot, iv);
            }
        }
    }
}

// ---------------------------------------------------------------------------
// conv: block owns 64 out rows. Slot rows staged ONCE into LDS (13.8 KB,
// coalesced int4). Wave owns 16 rows; kf=0..26: ds_read_b64 slot (broadcast
// across kg groups) -> 2 feat loads (row 0 L1-hot when empty) -> rare
// __any(c>1) dup-merge -> 8 chained MFMA. Global traffic = feat gathers +
// L1-hot W only. No atomics; 1 barrier. MFMA layouts r3-verified:
// A row=lane&15, k=(lane>>4)*8; C/D col=lane&15, row=(lane>>4)*4+reg.
// Out written exactly once (covers poison) + bias.
// ---------------------------------------------------------------------------
__global__ __launch_bounds__(256, 4) void conv_slots(
    const __bf16* __restrict__ featb,   // [N_ACTIVE][64] bf16
    const __bf16* __restrict__ wtb,     // [K][o][i] bf16
    const float* __restrict__ bias,     // [64]
    const int2* __restrict__ slotP,     // [N_ACTIVE][27] packed int2
    float* __restrict__ out)            // [N_ACTIVE][64] fp32
{
    __shared__ int2 sTab[64 * K_FILT];  // 13,824 B

    const int t = threadIdx.x;
    const int w = t >> 6;
    const int lane = t & 63;
    const int lrow = lane & 15;          // A/out row slot within tile
    const int kg   = lane >> 4;          // k-slice group (0..3)
    const int kgo  = kg * 8;
    const int rowBase = blockIdx.x * 64 + w * 16;

    // ---- stage slot table: 864 int4, fully coalesced ----
    {
        const int4* src = reinterpret_cast<const int4*>(slotP + (size_t)blockIdx.x * (64 * K_FILT));
        int4* dst = reinterpret_cast<int4*>(sTab);
        #pragma unroll
        for (int j = 0; j < 4; ++j) {
            int i = j * 256 + t;
            if (i < 864) dst[i] = src[i];
        }
    }
    __syncthreads();

    const int2* myRow = sTab + (w * 16 + lrow) * K_FILT;

    f32x4 acc0 = {0.f,0.f,0.f,0.f}, acc1 = acc0, acc2 = acc0, acc3 = acc0;
    const float b0 = bias[lrow], b1 = bias[16 + lrow],
                b2 = bias[32 + lrow], b3 = bias[48 + lrow];
    const bf16x8 zero8 = {};

    for (int kf = 0; kf < K_FILT; ++kf) {
        // ---- slot word from LDS (broadcast across kg groups) ----
        int2 sv = myRow[kf];
        int c  = ((unsigned)sv.x) >> 18;
        int a1 = (c > 0) ? (sv.x & 0x3FFFF) : 0;

        // ---- feat loads (row 0 L1-hot when empty) ----
        const __bf16* p1 = featb + (size_t)a1 * 64 + kgo;
        bf16x8 x0 = *reinterpret_cast<const bf16x8*>(p1);
        bf16x8 x1 = *reinterpret_cast<const bf16x8*>(p1 + 32);

        // ---- B fragments (L1/L2-hot) ----
        const __bf16* wk = wtb + kf * 4096;
        bf16x8 bf00 = *reinterpret_cast<const bf16x8*>(wk + (lrow)      * 64 + kgo);
        bf16x8 bf01 = *reinterpret_cast<const bf16x8*>(wk + (lrow)      * 64 + 32 + kgo);
        bf16x8 bf10 = *reinterpret_cast<const bf16x8*>(wk + (16 + lrow) * 64 + kgo);
        bf16x8 bf11 = *reinterpret_cast<const bf16x8*>(wk + (16 + lrow) * 64 + 32 + kgo);
        bf16x8 bf20 = *reinterpret_cast<const bf16x8*>(wk + (32 + lrow) * 64 + kgo);
        bf16x8 bf21 = *reinterpret_cast<const bf16x8*>(wk + (32 + lrow) * 64 + 32 + kgo);
        bf16x8 bf30 = *reinterpret_cast<const bf16x8*>(wk + (48 + lrow) * 64 + kgo);
        bf16x8 bf31 = *reinterpret_cast<const bf16x8*>(wk + (48 + lrow) * 64 + 32 + kgo);

        bf16x8 A0 = (c > 0) ? x0 : zero8;
        bf16x8 A1 = (c > 0) ? x1 : zero8;

        if (__any(c > 1)) {              // rare (~9% of slots): merge in2
            int a2 = (c > 1) ? sv.y : a1;        // a1 line is L1-hot
            const __bf16* p2 = featb + (size_t)a2 * 64 + kgo;
            bf16x8 y0 = *reinterpret_cast<const bf16x8*>(p2);
            bf16x8 y1 = *reinterpret_cast<const bf16x8*>(p2 + 32);
            y0 = (c > 1) ? y0 : zero8;
            y1 = (c > 1) ? y1 : zero8;
            #pragma unroll
            for (int j = 0; j < 8; ++j) {
                A0[j] = (__bf16)((float)A0[j] + (float)y0[j]);
                A1[j] = (__bf16)((float)A1[j] + (float)y1[j]);
            }
        }

        // ---- chained MFMA: acc += A(kf) * W(kf) ----
        acc0 = __builtin_amdgcn_mfma_f32_16x16x32_bf16(A0, bf00, acc0, 0, 0, 0);
        acc0 = __builtin_amdgcn_mfma_f32_16x16x32_bf16(A1, bf01, acc0, 0, 0, 0);
        acc1 = __builtin_amdgcn_mfma_f32_16x16x32_bf16(A0, bf10, acc1, 0, 0, 0);
        acc1 = __builtin_amdgcn_mfma_f32_16x16x32_bf16(A1, bf11, acc1, 0, 0, 0);
        acc2 = __builtin_amdgcn_mfma_f32_16x16x32_bf16(A0, bf20, acc2, 0, 0, 0);
        acc2 = __builtin_amdgcn_mfma_f32_16x16x32_bf16(A1, bf21, acc2, 0, 0, 0);
        acc3 = __builtin_amdgcn_mfma_f32_16x16x32_bf16(A0, bf30, acc3, 0, 0, 0);
        acc3 = __builtin_amdgcn_mfma_f32_16x16x32_bf16(A1, bf31, acc3, 0, 0, 0);
    }

    // ---- epilogue: C row = kg*4+r, col = n*16+lrow; nt-write once + bias ----
    #pragma unroll
    for (int r = 0; r < 4; ++r) {
        int gr = rowBase + kg * 4 + r;
        float* orow = out + (size_t)gr * 64;
        __builtin_nontemporal_store(acc0[r] + b0, &orow[lrow]);
        __builtin_nontemporal_store(acc1[r] + b1, &orow[16 + lrow]);
        __builtin_nontemporal_store(acc2[r] + b2, &orow[32 + lrow]);
        __builtin_nontemporal_store(acc3[r] + b3, &orow[48 + lrow]);
    }
}

// ---------------------------------------------------------------------------
// cleanup: overflow entries (3rd+ duplicate per slot, ~90K on random data).
// 64 threads = 64 out cols; dot(feat[in], Wt[kf][o]) + global fp32 atomicAdd.
// ---------------------------------------------------------------------------
__global__ __launch_bounds__(64) void ovf_cleanup(
    const __bf16* __restrict__ featb, const __bf16* __restrict__ wtb,
    const int2* __restrict__ ovf, const int* __restrict__ ovfCur,
    float* __restrict__ out)
{
    const int n = *ovfCur;
    const int lane = threadIdx.x;
    for (int e = blockIdx.x; e < n; e += gridDim.x) {
        int2 v = ovf[e];
        int slot = v.x, in = v.y;
        int row = slot / K_FILT;
        int kf  = slot - row * K_FILT;
        const __bf16* fp = featb + (size_t)in * 64;
        const __bf16* wp = wtb + kf * 4096 + lane * 64;
        float s = 0.f;
        #pragma unroll
        for (int j = 0; j < 8; ++j) {
            bf16x8 fv = *reinterpret_cast<const bf16x8*>(fp + j * 8);
            bf16x8 wv = *reinterpret_cast<const bf16x8*>(wp + j * 8);
            #pragma unroll
            for (int q = 0; q < 8; ++q) s += (float)fv[q] * (float)wv[q];
        }
        atomicAdd(&out[(size_t)row * 64 + lane], s);
    }
}

extern "C" void kernel_launch(void* const* d_in, const int* in_sizes, int n_in,
                              void* d_out, int out_size, void* d_ws, size_t ws_size,
                              hipStream_t stream) {
    const float* feat    = (const float*)d_in[0];
    const float* weight  = (const float*)d_in[1];
    const float* bias    = (const float*)d_in[2];
    const int*   in_idx  = (const int*)d_in[3];
    const int*   out_idx = (const int*)d_in[4];
    float* out = (float*)d_out;

    // ---- workspace layout (~91 MB) ----
    char* wsb = (char*)d_ws;
    __bf16* featb  = (__bf16*)wsb;                                  // 25,600,000
    __bf16* wtb    = (__bf16*)(wsb + 25600000);                     //    221,184
    int*  slotW    = (int*) (wsb + 25600000 + 221184);              // 43,200,000 (int2 packed)
    int*  ovfCur   = slotW + (size_t)NSLOT * 2;                     // 16 B (padded)
    int2* ovf      = (int2*)(ovfCur + 4);                           // 21,600,000

    hipMemsetAsync(slotW, 0, (size_t)NSLOT * 8, stream);
    hipMemsetAsync(ovfCur, 0, 16, stream);

    prep_fused<<<dim3(CF_BLOCKS + CW_BLOCKS + CL_BLOCKS), dim3(256), 0, stream>>>(
        feat, featb, weight, wtb, in_idx, out_idx, slotW, ovf, ovfCur);
    conv_slots<<<dim3(N_ACTIVE / 64), dim3(256), 0, stream>>>(
        featb, wtb, bias, (const int2*)slotW, out);
    ovf_cleanup<<<dim3(2048), dim3(64), 0, stream>>>(featb, wtb, ovf, ovfCur, out);
}

// Round 16
// 645.773 us; speedup vs baseline: 1.3780x; 1.3780x over previous
//
#include <hip/hip_runtime.h>
#include <stdint.h>

#define N_ACTIVE 200000
#define N_IN 64
#define N_OUT 64
#define K_FILT 27
#define R_PAIRS 100000
#define TOTP (K_FILT * R_PAIRS)          // 2,700,000
#define NSLOT (N_ACTIVE * K_FILT)        // 5,400,000 slots (row, kf)

#define CF_BLOCKS (N_ACTIVE * N_IN / 8 / 256)    // 6250
#define CW_BLOCKS K_FILT                          // 27
#define CL_BLOCKS ((TOTP + 255) / 256)            // 10547

typedef __bf16 bf16x8 __attribute__((ext_vector_type(8)));
typedef float f32x4 __attribute__((ext_vector_type(4)));

// ---------------------------------------------------------------------------
// fused prep: convert_feat | convert_wt | claim into PACKED int4 slot table
// slotT[slot] = (cnt, in1, in2, in3); 4th+ duplicate -> overflow list
// (r14 scheme: ONE atomic per pair + direct store — measured fastest prep)
// ---------------------------------------------------------------------------
__global__ __launch_bounds__(256) void prep_fused(
    const float* __restrict__ feat, __bf16* __restrict__ featb,
    const float* __restrict__ wsrc, __bf16* __restrict__ wt,
    const int* __restrict__ in_idx, const int* __restrict__ out_idx,
    int* __restrict__ slotW,            // int view of slotT
    int2* __restrict__ ovf, int* __restrict__ ovfCur)
{
    int bb = blockIdx.x, t = threadIdx.x;
    if (bb < CF_BLOCKS) {
        int i = bb * 256 + t;
        const f32x4* src = reinterpret_cast<const f32x4*>(feat) + 2 * (size_t)i;
        f32x4 v0 = __builtin_nontemporal_load(src);
        f32x4 v1 = __builtin_nontemporal_load(src + 1);
        bf16x8 o;
        o[0] = (__bf16)v0[0]; o[1] = (__bf16)v0[1]; o[2] = (__bf16)v0[2]; o[3] = (__bf16)v0[3];
        o[4] = (__bf16)v1[0]; o[5] = (__bf16)v1[1]; o[6] = (__bf16)v1[2]; o[7] = (__bf16)v1[3];
        reinterpret_cast<bf16x8*>(featb)[i] = o;
    } else if (bb < CF_BLOCKS + CW_BLOCKS) {
        int kf = bb - CF_BLOCKS;
        const float* wk = wsrc + kf * 4096;
        __bf16* wo = wt + kf * 4096;
        int o = t >> 2, i0 = (t & 3) * 16;
        bf16x8 a, b;
        #pragma unroll
        for (int j = 0; j < 8; ++j) a[j] = (__bf16)wk[(i0 + j) * 64 + o];
        #pragma unroll
        for (int j = 0; j < 8; ++j) b[j] = (__bf16)wk[(i0 + 8 + j) * 64 + o];
        *reinterpret_cast<bf16x8*>(wo + o * 64 + i0) = a;
        *reinterpret_cast<bf16x8*>(wo + o * 64 + i0 + 8) = b;
    } else {
        int p = (bb - CF_BLOCKS - CW_BLOCKS) * 256 + t;
        if (p < TOTP) {
            unsigned k = (unsigned)p / (unsigned)R_PAIRS;
            int row = out_idx[p];
            int iv  = in_idx[p];
            int slot = row * K_FILT + (int)k;
            int c = atomicAdd(&slotW[slot * 4], 1);
            if (c < 3) slotW[slot * 4 + 1 + c] = iv;
            else {
                int q = atomicAdd(ovfCur, 1);
                ovf[q] = make_int2(slot, iv);
            }
        }
    }
}

// ---------------------------------------------------------------------------
// conv: block owns 64 out rows. int4 slot table staged ONCE into LDS
// (27.6 KB, coalesced). Wave owns 16 rows; kf loop runs an EXPLICIT 2-deep
// pipeline: issue kf+1's slot-read + both feat loads BEFORE consuming kf
// (named rotating registers -> ~4 gathers in flight per wave). Rare
// __any(c>1) merge path. No atomics; 1 barrier. MFMA layouts r3-verified:
// A row=lane&15, k=(lane>>4)*8; C/D col=lane&15, row=(lane>>4)*4+reg.
// Out written exactly once (covers poison) + bias.
// ---------------------------------------------------------------------------
__global__ __launch_bounds__(256, 4) void conv_slots(
    const __bf16* __restrict__ featb,   // [N_ACTIVE][64] bf16
    const __bf16* __restrict__ wtb,     // [K][o][i] bf16
    const float* __restrict__ bias,     // [64]
    const int4* __restrict__ slotT,     // [N_ACTIVE][27] packed
    float* __restrict__ out)            // [N_ACTIVE][64] fp32
{
    __shared__ int4 sTab[64 * K_FILT];  // 27,648 B

    const int t = threadIdx.x;
    const int w = t >> 6;
    const int lane = t & 63;
    const int lrow = lane & 15;          // A/out row slot within tile
    const int kg   = lane >> 4;          // k-slice group (0..3)
    const int kgo  = kg * 8;
    const int rowBase = blockIdx.x * 64 + w * 16;

    // ---- stage slot table: 1728 int4, fully coalesced ----
    {
        const int4* src = slotT + (size_t)blockIdx.x * (64 * K_FILT);
        #pragma unroll
        for (int j = 0; j < 7; ++j) {
            int i = j * 256 + t;
            if (i < 64 * K_FILT) sTab[i] = src[i];
        }
    }
    __syncthreads();

    const int4* myRow = sTab + (w * 16 + lrow) * K_FILT;

    f32x4 acc0 = {0.f,0.f,0.f,0.f}, acc1 = acc0, acc2 = acc0, acc3 = acc0;
    const float b0 = bias[lrow], b1 = bias[16 + lrow],
                b2 = bias[32 + lrow], b3 = bias[48 + lrow];
    const bf16x8 zero8 = {};

    // ---- prologue: load slot 0's feat fragments ----
    int4 sv = myRow[0];
    {
        int a1 = (sv.x > 0) ? sv.y : 0;
        (void)a1;
    }
    int a1c = (sv.x > 0) ? sv.y : 0;
    const __bf16* p1c = featb + (size_t)a1c * 64 + kgo;
    bf16x8 x0 = *reinterpret_cast<const bf16x8*>(p1c);
    bf16x8 x1 = *reinterpret_cast<const bf16x8*>(p1c + 32);

    for (int kf = 0; kf < K_FILT; ++kf) {
        // ---- PREFETCH kf+1: slot from LDS + 2 independent feat loads ----
        int nk = (kf + 1 < K_FILT) ? kf + 1 : K_FILT - 1;
        int4 svn = myRow[nk];
        int a1n = (svn.x > 0) ? svn.y : 0;
        const __bf16* p1n = featb + (size_t)a1n * 64 + kgo;
        bf16x8 nx0 = *reinterpret_cast<const bf16x8*>(p1n);
        bf16x8 nx1 = *reinterpret_cast<const bf16x8*>(p1n + 32);

        // ---- B fragments (L1/L2-hot) ----
        const __bf16* wk = wtb + kf * 4096;
        bf16x8 bf00 = *reinterpret_cast<const bf16x8*>(wk + (lrow)      * 64 + kgo);
        bf16x8 bf01 = *reinterpret_cast<const bf16x8*>(wk + (lrow)      * 64 + 32 + kgo);
        bf16x8 bf10 = *reinterpret_cast<const bf16x8*>(wk + (16 + lrow) * 64 + kgo);
        bf16x8 bf11 = *reinterpret_cast<const bf16x8*>(wk + (16 + lrow) * 64 + 32 + kgo);
        bf16x8 bf20 = *reinterpret_cast<const bf16x8*>(wk + (32 + lrow) * 64 + kgo);
        bf16x8 bf21 = *reinterpret_cast<const bf16x8*>(wk + (32 + lrow) * 64 + 32 + kgo);
        bf16x8 bf30 = *reinterpret_cast<const bf16x8*>(wk + (48 + lrow) * 64 + kgo);
        bf16x8 bf31 = *reinterpret_cast<const bf16x8*>(wk + (48 + lrow) * 64 + 32 + kgo);

        // ---- consume kf ----
        int c = sv.x;
        bf16x8 A0 = (c > 0) ? x0 : zero8;
        bf16x8 A1 = (c > 0) ? x1 : zero8;

        if (__any(c > 1)) {              // rare: merge in2 (and rarer in3)
            int a2 = (c > 1) ? sv.z : a1c;       // a1 line is L1-hot
            int a3 = (c > 2) ? sv.w : a1c;
            const __bf16* p2 = featb + (size_t)a2 * 64 + kgo;
            const __bf16* p3 = featb + (size_t)a3 * 64 + kgo;
            bf16x8 y0 = *reinterpret_cast<const bf16x8*>(p2);
            bf16x8 y1 = *reinterpret_cast<const bf16x8*>(p2 + 32);
            bf16x8 z0 = *reinterpret_cast<const bf16x8*>(p3);
            bf16x8 z1 = *reinterpret_cast<const bf16x8*>(p3 + 32);
            y0 = (c > 1) ? y0 : zero8;  y1 = (c > 1) ? y1 : zero8;
            z0 = (c > 2) ? z0 : zero8;  z1 = (c > 2) ? z1 : zero8;
            #pragma unroll
            for (int j = 0; j < 8; ++j) {
                A0[j] = (__bf16)((float)A0[j] + (float)y0[j] + (float)z0[j]);
                A1[j] = (__bf16)((float)A1[j] + (float)y1[j] + (float)z1[j]);
            }
        }

        // ---- chained MFMA: acc += A(kf) * W(kf) ----
        acc0 = __builtin_amdgcn_mfma_f32_16x16x32_bf16(A0, bf00, acc0, 0, 0, 0);
        acc0 = __builtin_amdgcn_mfma_f32_16x16x32_bf16(A1, bf01, acc0, 0, 0, 0);
        acc1 = __builtin_amdgcn_mfma_f32_16x16x32_bf16(A0, bf10, acc1, 0, 0, 0);
        acc1 = __builtin_amdgcn_mfma_f32_16x16x32_bf16(A1, bf11, acc1, 0, 0, 0);
        acc2 = __builtin_amdgcn_mfma_f32_16x16x32_bf16(A0, bf20, acc2, 0, 0, 0);
        acc2 = __builtin_amdgcn_mfma_f32_16x16x32_bf16(A1, bf21, acc2, 0, 0, 0);
        acc3 = __builtin_amdgcn_mfma_f32_16x16x32_bf16(A0, bf30, acc3, 0, 0, 0);
        acc3 = __builtin_amdgcn_mfma_f32_16x16x32_bf16(A1, bf31, acc3, 0, 0, 0);

        // ---- rotate pipeline registers ----
        sv = svn; a1c = a1n; x0 = nx0; x1 = nx1;
    }

    // ---- epilogue: C row = kg*4+r, col = n*16+lrow; nt-write once + bias ----
    #pragma unroll
    for (int r = 0; r < 4; ++r) {
        int gr = rowBase + kg * 4 + r;
        float* orow = out + (size_t)gr * 64;
        __builtin_nontemporal_store(acc0[r] + b0, &orow[lrow]);
        __builtin_nontemporal_store(acc1[r] + b1, &orow[16 + lrow]);
        __builtin_nontemporal_store(acc2[r] + b2, &orow[32 + lrow]);
        __builtin_nontemporal_store(acc3[r] + b3, &orow[48 + lrow]);
    }
}

// ---------------------------------------------------------------------------
// cleanup: overflow entries (4th+ duplicate per slot, E ~ 10K random data).
// 64 threads = 64 out cols; dot(feat[in], Wt[kf][o]) + global fp32 atomicAdd.
// ---------------------------------------------------------------------------
__global__ __launch_bounds__(64) void ovf_cleanup(
    const __bf16* __restrict__ featb, const __bf16* __restrict__ wtb,
    const int2* __restrict__ ovf, const int* __restrict__ ovfCur,
    float* __restrict__ out)
{
    const int n = *ovfCur;
    const int lane = threadIdx.x;
    for (int e = blockIdx.x; e < n; e += gridDim.x) {
        int2 v = ovf[e];
        int slot = v.x, in = v.y;
        int row = slot / K_FILT;
        int kf  = slot - row * K_FILT;
        const __bf16* fp = featb + (size_t)in * 64;
        const __bf16* wp = wtb + kf * 4096 + lane * 64;
        float s = 0.f;
        #pragma unroll
        for (int j = 0; j < 8; ++j) {
            bf16x8 fv = *reinterpret_cast<const bf16x8*>(fp + j * 8);
            bf16x8 wv = *reinterpret_cast<const bf16x8*>(wp + j * 8);
            #pragma unroll
            for (int q = 0; q < 8; ++q) s += (float)fv[q] * (float)wv[q];
        }
        atomicAdd(&out[(size_t)row * 64 + lane], s);
    }
}

extern "C" void kernel_launch(void* const* d_in, const int* in_sizes, int n_in,
                              void* d_out, int out_size, void* d_ws, size_t ws_size,
                              hipStream_t stream) {
    const float* feat    = (const float*)d_in[0];
    const float* weight  = (const float*)d_in[1];
    const float* bias    = (const float*)d_in[2];
    const int*   in_idx  = (const int*)d_in[3];
    const int*   out_idx = (const int*)d_in[4];
    float* out = (float*)d_out;

    // ---- workspace layout (~134 MB) ----
    char* wsb = (char*)d_ws;
    __bf16* featb  = (__bf16*)wsb;                                  // 25,600,000
    __bf16* wtb    = (__bf16*)(wsb + 25600000);                     //    221,184
    int*  slotW    = (int*) (wsb + 25600000 + 221184);              // 86,400,000 (int4)
    int*  ovfCur   = slotW + (size_t)NSLOT * 4;                     // 16 B (padded)
    int2* ovf      = (int2*)(ovfCur + 4);                           // 21,600,000

    hipMemsetAsync(slotW, 0, (size_t)NSLOT * 16, stream);
    hipMemsetAsync(ovfCur, 0, 16, stream);

    prep_fused<<<dim3(CF_BLOCKS + CW_BLOCKS + CL_BLOCKS), dim3(256), 0, stream>>>(
        feat, featb, weight, wtb, in_idx, out_idx, slotW, ovf, ovfCur);
    conv_slots<<<dim3(N_ACTIVE / 64), dim3(256), 0, stream>>>(
        featb, wtb, bias, (const int4*)slotW, out);
    ovf_cleanup<<<dim3(2048), dim3(64), 0, stream>>>(featb, wtb, ovf, ovfCur, out);
}

// Round 18
// 645.379 us; speedup vs baseline: 1.3789x; 1.0006x over previous
//
#include <hip/hip_runtime.h>
#include <stdint.h>

#define N_ACTIVE 200000
#define N_IN 64
#define N_OUT 64
#define K_FILT 27
#define R_PAIRS 100000
#define TOTP (K_FILT * R_PAIRS)          // 2,700,000
#define NSLOT (N_ACTIVE * K_FILT)        // 5,400,000 slots (row, kf)

#define CF_BLOCKS (N_ACTIVE * N_IN / 8 / 256)    // 6250
#define CW_BLOCKS K_FILT                          // 27
#define CL_BLOCKS ((TOTP + 255) / 256)            // 10547

typedef __bf16 bf16x8 __attribute__((ext_vector_type(8)));
typedef float f32x4 __attribute__((ext_vector_type(4)));
typedef int   i32x4 __attribute__((ext_vector_type(4)));

// ---------------------------------------------------------------------------
// fused prep: convert_feat | convert_wt | claim into PACKED int4 slot table
// slotT[slot] = (cnt, in1, in2, in3); 4th+ duplicate -> overflow list
// (single atomic + direct store per pair — measured fastest claim, r14)
// ---------------------------------------------------------------------------
__global__ __launch_bounds__(256) void prep_fused(
    const float* __restrict__ feat, __bf16* __restrict__ featb,
    const float* __restrict__ wsrc, __bf16* __restrict__ wt,
    const int* __restrict__ in_idx, const int* __restrict__ out_idx,
    int* __restrict__ slotW,            // int view of slotT
    int2* __restrict__ ovf, int* __restrict__ ovfCur)
{
    int bb = blockIdx.x, t = threadIdx.x;
    if (bb < CF_BLOCKS) {
        int i = bb * 256 + t;
        const f32x4* src = reinterpret_cast<const f32x4*>(feat) + 2 * (size_t)i;
        f32x4 v0 = __builtin_nontemporal_load(src);
        f32x4 v1 = __builtin_nontemporal_load(src + 1);
        bf16x8 o;
        o[0] = (__bf16)v0[0]; o[1] = (__bf16)v0[1]; o[2] = (__bf16)v0[2]; o[3] = (__bf16)v0[3];
        o[4] = (__bf16)v1[0]; o[5] = (__bf16)v1[1]; o[6] = (__bf16)v1[2]; o[7] = (__bf16)v1[3];
        reinterpret_cast<bf16x8*>(featb)[i] = o;
    } else if (bb < CF_BLOCKS + CW_BLOCKS) {
        int kf = bb - CF_BLOCKS;
        const float* wk = wsrc + kf * 4096;
        __bf16* wo = wt + kf * 4096;
        int o = t >> 2, i0 = (t & 3) * 16;
        bf16x8 a, b;
        #pragma unroll
        for (int j = 0; j < 8; ++j) a[j] = (__bf16)wk[(i0 + j) * 64 + o];
        #pragma unroll
        for (int j = 0; j < 8; ++j) b[j] = (__bf16)wk[(i0 + 8 + j) * 64 + o];
        *reinterpret_cast<bf16x8*>(wo + o * 64 + i0) = a;
        *reinterpret_cast<bf16x8*>(wo + o * 64 + i0 + 8) = b;
    } else {
        int p = (bb - CF_BLOCKS - CW_BLOCKS) * 256 + t;
        if (p < TOTP) {
            unsigned k = (unsigned)p / (unsigned)R_PAIRS;
            int row = __builtin_nontemporal_load(&out_idx[p]);
            int iv  = __builtin_nontemporal_load(&in_idx[p]);
            int slot = row * K_FILT + (int)k;
            int c = atomicAdd(&slotW[slot * 4], 1);
            if (c < 3) slotW[slot * 4 + 1 + c] = iv;
            else {
                int q = atomicAdd(ovfCur, 1);
                ovf[q] = make_int2(slot, iv);
            }
        }
    }
}

// ---------------------------------------------------------------------------
// conv: block owns 64 out rows. int4 slot table staged ONCE into LDS via
// NONTEMPORAL loads (one-touch 86-MB stream must not evict featb from L3).
// Wave owns 16 rows; kf=0..26: LDS slot read -> 2 temporal feat loads
// (row 0 L1-hot when empty) -> rare __any(c>1) dup merge -> 8 chained MFMA.
// No atomics; 1 barrier. MFMA layouts r3-verified: A row=lane&15,
// k=(lane>>4)*8; C/D col=lane&15, row=(lane>>4)*4+reg.
// Out written exactly once (covers poison) + bias, nt stores.
// ---------------------------------------------------------------------------
__global__ __launch_bounds__(256, 4) void conv_slots(
    const __bf16* __restrict__ featb,   // [N_ACTIVE][64] bf16
    const __bf16* __restrict__ wtb,     // [K][o][i] bf16
    const float* __restrict__ bias,     // [64]
    const int4* __restrict__ slotT,     // [N_ACTIVE][27] packed
    float* __restrict__ out)            // [N_ACTIVE][64] fp32
{
    __shared__ int4 sTab[64 * K_FILT];  // 27,648 B

    const int t = threadIdx.x;
    const int w = t >> 6;
    const int lane = t & 63;
    const int lrow = lane & 15;          // A/out row slot within tile
    const int kg   = lane >> 4;          // k-slice group (0..3)
    const int kgo  = kg * 8;
    const int rowBase = blockIdx.x * 64 + w * 16;

    // ---- stage slot table: 1728 int4, coalesced, NONTEMPORAL ----
    {
        const i32x4* src = reinterpret_cast<const i32x4*>(
            slotT + (size_t)blockIdx.x * (64 * K_FILT));
        i32x4* dst = reinterpret_cast<i32x4*>(sTab);
        #pragma unroll
        for (int j = 0; j < 7; ++j) {
            int i = j * 256 + t;
            if (i < 64 * K_FILT) dst[i] = __builtin_nontemporal_load(&src[i]);
        }
    }
    __syncthreads();

    const int4* myRow = sTab + (w * 16 + lrow) * K_FILT;

    f32x4 acc0 = {0.f,0.f,0.f,0.f}, acc1 = acc0, acc2 = acc0, acc3 = acc0;
    const float b0 = bias[lrow], b1 = bias[16 + lrow],
                b2 = bias[32 + lrow], b3 = bias[48 + lrow];
    const bf16x8 zero8 = {};

    for (int kf = 0; kf < K_FILT; ++kf) {
        // ---- slot word from LDS ----
        int4 sv = myRow[kf];
        int c  = sv.x;
        int a1 = (c > 0) ? sv.y : 0;

        // ---- feat loads (temporal: featb is the L3-resident hot set) ----
        const __bf16* p1 = featb + (size_t)a1 * 64 + kgo;
        bf16x8 x0 = *reinterpret_cast<const bf16x8*>(p1);
        bf16x8 x1 = *reinterpret_cast<const bf16x8*>(p1 + 32);

        // ---- B fragments (L1/L2-hot, 216 KB total) ----
        const __bf16* wk = wtb + kf * 4096;
        bf16x8 bf00 = *reinterpret_cast<const bf16x8*>(wk + (lrow)      * 64 + kgo);
        bf16x8 bf01 = *reinterpret_cast<const bf16x8*>(wk + (lrow)      * 64 + 32 + kgo);
        bf16x8 bf10 = *reinterpret_cast<const bf16x8*>(wk + (16 + lrow) * 64 + kgo);
        bf16x8 bf11 = *reinterpret_cast<const bf16x8*>(wk + (16 + lrow) * 64 + 32 + kgo);
        bf16x8 bf20 = *reinterpret_cast<const bf16x8*>(wk + (32 + lrow) * 64 + kgo);
        bf16x8 bf21 = *reinterpret_cast<const bf16x8*>(wk + (32 + lrow) * 64 + 32 + kgo);
        bf16x8 bf30 = *reinterpret_cast<const bf16x8*>(wk + (48 + lrow) * 64 + kgo);
        bf16x8 bf31 = *reinterpret_cast<const bf16x8*>(wk + (48 + lrow) * 64 + 32 + kgo);

        bf16x8 A0 = (c > 0) ? x0 : zero8;
        bf16x8 A1 = (c > 0) ? x1 : zero8;

        if (__any(c > 1)) {              // rare: merge in2 (and rarer in3)
            int a2 = (c > 1) ? sv.z : a1;        // a1 line is L1-hot
            int a3 = (c > 2) ? sv.w : a1;
            const __bf16* p2 = featb + (size_t)a2 * 64 + kgo;
            const __bf16* p3 = featb + (size_t)a3 * 64 + kgo;
            bf16x8 y0 = *reinterpret_cast<const bf16x8*>(p2);
            bf16x8 y1 = *reinterpret_cast<const bf16x8*>(p2 + 32);
            bf16x8 z0 = *reinterpret_cast<const bf16x8*>(p3);
            bf16x8 z1 = *reinterpret_cast<const bf16x8*>(p3 + 32);
            y0 = (c > 1) ? y0 : zero8;  y1 = (c > 1) ? y1 : zero8;
            z0 = (c > 2) ? z0 : zero8;  z1 = (c > 2) ? z1 : zero8;
            #pragma unroll
            for (int j = 0; j < 8; ++j) {
                A0[j] = (__bf16)((float)A0[j] + (float)y0[j] + (float)z0[j]);
                A1[j] = (__bf16)((float)A1[j] + (float)y1[j] + (float)z1[j]);
            }
        }

        // ---- chained MFMA: acc += A(kf) * W(kf) ----
        acc0 = __builtin_amdgcn_mfma_f32_16x16x32_bf16(A0, bf00, acc0, 0, 0, 0);
        acc0 = __builtin_amdgcn_mfma_f32_16x16x32_bf16(A1, bf01, acc0, 0, 0, 0);
        acc1 = __builtin_amdgcn_mfma_f32_16x16x32_bf16(A0, bf10, acc1, 0, 0, 0);
        acc1 = __builtin_amdgcn_mfma_f32_16x16x32_bf16(A1, bf11, acc1, 0, 0, 0);
        acc2 = __builtin_amdgcn_mfma_f32_16x16x32_bf16(A0, bf20, acc2, 0, 0, 0);
        acc2 = __builtin_amdgcn_mfma_f32_16x16x32_bf16(A1, bf21, acc2, 0, 0, 0);
        acc3 = __builtin_amdgcn_mfma_f32_16x16x32_bf16(A0, bf30, acc3, 0, 0, 0);
        acc3 = __builtin_amdgcn_mfma_f32_16x16x32_bf16(A1, bf31, acc3, 0, 0, 0);
    }

    // ---- epilogue: C row = kg*4+r, col = n*16+lrow; nt-write once + bias ----
    #pragma unroll
    for (int r = 0; r < 4; ++r) {
        int gr = rowBase + kg * 4 + r;
        float* orow = out + (size_t)gr * 64;
        __builtin_nontemporal_store(acc0[r] + b0, &orow[lrow]);
        __builtin_nontemporal_store(acc1[r] + b1, &orow[16 + lrow]);
        __builtin_nontemporal_store(acc2[r] + b2, &orow[32 + lrow]);
        __builtin_nontemporal_store(acc3[r] + b3, &orow[48 + lrow]);
    }
}

// ---------------------------------------------------------------------------
// cleanup: overflow entries (4th+ duplicate per slot, E ~ 10K random data).
// 64 threads = 64 out cols; dot(feat[in], Wt[kf][o]) + global fp32 atomicAdd.
// ---------------------------------------------------------------------------
__global__ __launch_bounds__(64) void ovf_cleanup(
    const __bf16* __restrict__ featb, const __bf16* __restrict__ wtb,
    const int2* __restrict__ ovf, const int* __restrict__ ovfCur,
    float* __restrict__ out)
{
    const int n = *ovfCur;
    const int lane = threadIdx.x;
    for (int e = blockIdx.x; e < n; e += gridDim.x) {
        int2 v = ovf[e];
        int slot = v.x, in = v.y;
        int row = slot / K_FILT;
        int kf  = slot - row * K_FILT;
        const __bf16* fp = featb + (size_t)in * 64;
        const __bf16* wp = wtb + kf * 4096 + lane * 64;
        float s = 0.f;
        #pragma unroll
        for (int j = 0; j < 8; ++j) {
            bf16x8 fv = *reinterpret_cast<const bf16x8*>(fp + j * 8);
            bf16x8 wv = *reinterpret_cast<const bf16x8*>(wp + j * 8);
            #pragma unroll
            for (int q = 0; q < 8; ++q) s += (float)fv[q] * (float)wv[q];
        }
        atomicAdd(&out[(size_t)row * 64 + lane], s);
    }
}

extern "C" void kernel_launch(void* const* d_in, const int* in_sizes, int n_in,
                              void* d_out, int out_size, void* d_ws, size_t ws_size,
                              hipStream_t stream) {
    const float* feat    = (const float*)d_in[0];
    const float* weight  = (const float*)d_in[1];
    const float* bias    = (const float*)d_in[2];
    const int*   in_idx  = (const int*)d_in[3];
    const int*   out_idx = (const int*)d_in[4];
    float* out = (float*)d_out;

    // ---- workspace layout (~134 MB) ----
    char* wsb = (char*)d_ws;
    __bf16* featb  = (__bf16*)wsb;                                  // 25,600,000
    __bf16* wtb    = (__bf16*)(wsb + 25600000);                     //    221,184
    int*  slotW    = (int*) (wsb + 25600000 + 221184);              // 86,400,000 (int4)
    int*  ovfCur   = slotW + (size_t)NSLOT * 4;                     // 16 B (padded)
    int2* ovf      = (int2*)(ovfCur + 4);                           // 21,600,000

    (void)hipMemsetAsync(slotW, 0, (size_t)NSLOT * 16, stream);
    (void)hipMemsetAsync(ovfCur, 0, 16, stream);

    prep_fused<<<dim3(CF_BLOCKS + CW_BLOCKS + CL_BLOCKS), dim3(256), 0, stream>>>(
        feat, featb, weight, wtb, in_idx, out_idx, slotW, ovf, ovfCur);
    conv_slots<<<dim3(N_ACTIVE / 64), dim3(256), 0, stream>>>(
        featb, wtb, bias, (const int4*)slotW, out);
    ovf_cleanup<<<dim3(2048), dim3(64), 0, stream>>>(featb, wtb, ovf, ovfCur, out);
}